// Round 3
// baseline (279.660 us; speedup 1.0000x reference)
//
#include <hip/hip_runtime.h>
#include <hip/hip_bf16.h>

// Problem: B=8, C=256, H=W=64 -> N=4096, inter=32. fp32 in/out.
#define BB 8
#define CC 256
#define NN 4096
#define II 32

typedef __bf16 bf16_t;
typedef bf16_t bf16x8 __attribute__((ext_vector_type(8)));
typedef float f32x4 __attribute__((ext_vector_type(4)));

// ---------------------------------------------------------------------------
// Weight pre-convert: Wb[320][256] bf16 = [Wq(32); Wk(32); Wv(256)] rows.
// ---------------------------------------------------------------------------
__global__ __launch_bounds__(256) void wconv(
    const float* __restrict__ Wq, const float* __restrict__ Wk,
    const float* __restrict__ Wv, bf16_t* __restrict__ Wb) {
  int idx = blockIdx.x * 256 + threadIdx.x;  // < 320*256
  int o = idx >> 8, c = idx & 255;
  float w = (o < 32) ? Wq[o * 256 + c]
          : (o < 64) ? Wk[(o - 32) * 256 + c]
                     : Wv[(o - 64) * 256 + c];
  Wb[idx] = (bf16_t)w;
}

// ---------------------------------------------------------------------------
// x transpose+convert: xt[b][n][c] bf16 from x[b][c][n] fp32.
// ---------------------------------------------------------------------------
__global__ __launch_bounds__(256) void xcvt(
    const float* __restrict__ x, bf16_t* __restrict__ xt) {
  __shared__ bf16_t tl[64][72];  // [n][c], padded
  const int t  = threadIdx.x;
  const int n0 = blockIdx.x * 64, c0 = blockIdx.y * 64, b = blockIdx.z;

  const float* xb = x + ((size_t)b * CC + c0) * NN + n0;
#pragma unroll
  for (int p = 0; p < 4; ++p) {
    int cl = (t >> 4) + 16 * p;
    int nl = (t & 15) * 4;
    float4 v = *(const float4*)&xb[(size_t)cl * NN + nl];
    tl[nl + 0][cl] = (bf16_t)v.x;
    tl[nl + 1][cl] = (bf16_t)v.y;
    tl[nl + 2][cl] = (bf16_t)v.z;
    tl[nl + 3][cl] = (bf16_t)v.w;
  }
  __syncthreads();
  bf16_t* xtb = xt + ((size_t)b * NN + n0) * CC + c0;
#pragma unroll
  for (int p = 0; p < 4; ++p) {
    int nl = (t >> 4) + 16 * p;
    int cl = (t & 15) * 4;
    union { bf16_t h[4]; uint2 u; } pk;
    pk.h[0] = tl[nl][cl + 0]; pk.h[1] = tl[nl][cl + 1];
    pk.h[2] = tl[nl][cl + 2]; pk.h[3] = tl[nl][cl + 3];
    *(uint2*)&xtb[(size_t)nl * CC + cl] = pk.u;
  }
}

// ---------------------------------------------------------------------------
// Fused q/k/v projection as MFMA GEMM (unchanged).
// ---------------------------------------------------------------------------
__global__ __launch_bounds__(256, 4) void qkv_proj(
    const bf16_t* __restrict__ xt, const bf16_t* __restrict__ Wb,
    const float* __restrict__ bq, const float* __restrict__ bk,
    const float* __restrict__ bv,
    bf16_t* __restrict__ q, bf16_t* __restrict__ k, bf16_t* __restrict__ v) {
  const int t  = threadIdx.x;
  const int w  = t >> 6;
  const int l  = t & 63;
  const int lo = l & 15;
  const int q4 = l >> 4;
  const int og = blockIdx.y;  // o-tile group: tiles [og*5, og*5+5)
  const int b  = blockIdx.z;
  const int nbase = blockIdx.x * 128 + w * 32;

  const bf16_t* xb = xt + (size_t)b * NN * CC;

  f32x4 acc[5][2];  // [o-tile][n-subtile]
#pragma unroll
  for (int ot = 0; ot < 5; ++ot)
#pragma unroll
    for (int ms = 0; ms < 2; ++ms) acc[ot][ms] = (f32x4){0.f, 0.f, 0.f, 0.f};

#pragma unroll 2
  for (int ks = 0; ks < 8; ++ks) {
    const int c0 = ks * 32 + q4 * 8;
    bf16x8 af[2];
#pragma unroll
    for (int ms = 0; ms < 2; ++ms)
      af[ms] = *(const bf16x8*)&xb[(size_t)(nbase + ms * 16 + lo) * CC + c0];
    bf16x8 bw[5];
#pragma unroll
    for (int ot = 0; ot < 5; ++ot)
      bw[ot] = *(const bf16x8*)&Wb[((og * 5 + ot) * 16 + lo) * 256 + c0];
#pragma unroll
    for (int ms = 0; ms < 2; ++ms)
#pragma unroll
      for (int ot = 0; ot < 5; ++ot)
        acc[ot][ms] = __builtin_amdgcn_mfma_f32_16x16x32_bf16(
            af[ms], bw[ot], acc[ot][ms], 0, 0, 0);
  }

  // Epilogue: q,k -> [b][n][32] bf16 (2B scatter); v -> [b][c][n] bf16.
#pragma unroll
  for (int ot = 0; ot < 5; ++ot) {
    const int gt = og * 5 + ot;  // global o-tile
    if (gt < 4) {
      const bool isq = gt < 2;
      const int i = (gt & 1) * 16 + lo;
      const float bias = isq ? bq[i] : bk[i];
      bf16_t* dst = (isq ? q : k) + (size_t)b * NN * II;
#pragma unroll
      for (int ms = 0; ms < 2; ++ms) {
#pragma unroll
        for (int r = 0; r < 4; ++r) {
          int n = nbase + ms * 16 + q4 * 4 + r;
          dst[(size_t)n * II + i] = (bf16_t)(acc[ot][ms][r] + bias);
        }
      }
    } else {
      const int cv = (gt - 4) * 16 + lo;
      const float bias = bv[cv];
      bf16_t* dst = v + ((size_t)b * CC + cv) * NN;
#pragma unroll
      for (int ms = 0; ms < 2; ++ms) {
        union { bf16_t h[4]; uint2 u; } pk;
#pragma unroll
        for (int r = 0; r < 4; ++r) pk.h[r] = (bf16_t)(acc[ot][ms][r] + bias);
        *(uint2*)&dst[nbase + ms * 16 + q4 * 4] = pk.u;
      }
    }
  }
}

// ---------------------------------------------------------------------------
// Zero-shuffle MFMA attention. No LDS, no barriers; waves fully independent.
// Wave: m-tile 64 (4 mt), c-sub 64 (4 ct). Block = 4 waves = 4 adjacent
// m-tiles sharing ONE c-split -> identical V streams, L1 dedups 4x.
// Per 32-n chunk:
//   QK: S[32n][64m] via 8 mfma(kf[s], qf[mt]). K rows are loaded PERMUTED:
//       lane lo of sub s holds K row (lo>>2)*8 + s*4 + (lo&3). Then lane
//       (lo,q4) reg r of sub s gets S[n = q4*8+s*4+r][m = lo] -- exactly the
//       8 consecutive n this lane needs as the PV A-operand (P[m=lo][q4*8+j]).
//   exp -> 8 bf16 per mt -> pf[mt] directly (zero cross-lane traffic).
//   PV: acc[mt][ct] = mfma(pf[mt], vf[ct], acc) -> O[m][c],
//       lane (lo,q4) reg r: O[m = mt*16+q4*4+r][c = ct*16+lo].
// QK replicated x4 (one per c-split): MFMA floor (68.7+4*8.6)GF ~ 50us.
// lp (denom) is wave-local: reduce over q4 groups with 2 shfl_xor at end.
// Epilogue: contiguous float4 x-load / out-store per (mt,ct).
// XCD swizzle: batch = bid&7 -> all 64 blocks of a batch on one XCD;
// V[b] (2MB) + K[b] (256KB) fit the 4MB per-XCD L2.
// ---------------------------------------------------------------------------
__global__ __launch_bounds__(256, 2) void attn_zs(
    const bf16_t* __restrict__ q, const bf16_t* __restrict__ k,
    const bf16_t* __restrict__ v, const float* __restrict__ x,
    const float* __restrict__ gamma, float* __restrict__ out) {
  const int t  = threadIdx.x;
  const int w  = t >> 6;
  const int l  = t & 63;
  const int lo = l & 15;
  const int q4 = l >> 4;

  const int bid  = blockIdx.x;
  const int b    = bid & 7;        // XCD-aligned batch
  const int rest = bid >> 3;
  const int cs   = rest & 3;       // c-split
  const int mg   = rest >> 2;      // m-group (4 m-tiles)
  const int m0   = (mg * 4 + w) * 64;
  const int cb   = cs * 64;

  const bf16_t* qb = q + (size_t)b * NN * II;
  const bf16_t* kb = k + (size_t)b * NN * II;
  const bf16_t* vb = v + (size_t)b * CC * NN;

  // Q B-frags, loop-invariant
  bf16x8 qf[4];
#pragma unroll
  for (int mt = 0; mt < 4; ++mt)
    qf[mt] = *(const bf16x8*)(qb + (size_t)(m0 + mt * 16 + lo) * II + q4 * 8);

  f32x4 acc[4][4];  // [mt][ct]
#pragma unroll
  for (int mt = 0; mt < 4; ++mt)
#pragma unroll
    for (int ct = 0; ct < 4; ++ct) acc[mt][ct] = (f32x4){0.f, 0.f, 0.f, 0.f};
  float lp[4] = {0.f, 0.f, 0.f, 0.f};

  const f32x4 zero = (f32x4){0.f, 0.f, 0.f, 0.f};
  const int kperm = ((lo >> 2) << 3) | (lo & 3);  // + s*4 + n1

  // Prime chunk 0
  bf16x8 kf0 = *(const bf16x8*)(kb + (size_t)(kperm + 0) * II + q4 * 8);
  bf16x8 kf1 = *(const bf16x8*)(kb + (size_t)(kperm + 4) * II + q4 * 8);
  bf16x8 vf[4];
#pragma unroll
  for (int ct = 0; ct < 4; ++ct)
    vf[ct] = *(const bf16x8*)(vb + (size_t)(cb + ct * 16 + lo) * NN + q4 * 8);

#pragma unroll 2
  for (int n1 = 0; n1 < NN; n1 += 32) {
    // ---- prefetch next chunk's K/V frags (consumed next iteration) ----
    const int nn = (n1 + 32) & (NN - 1);  // wraps on last iter (discarded)
    bf16x8 kf0n = *(const bf16x8*)(kb + (size_t)(nn + kperm + 0) * II + q4 * 8);
    bf16x8 kf1n = *(const bf16x8*)(kb + (size_t)(nn + kperm + 4) * II + q4 * 8);
    bf16x8 vfn[4];
#pragma unroll
    for (int ct = 0; ct < 4; ++ct)
      vfn[ct] = *(const bf16x8*)(vb + (size_t)(cb + ct * 16 + lo) * NN + nn + q4 * 8);

    // ---- QK + exp + pack (all lane-local) ----
    bf16x8 pf[4];
#pragma unroll
    for (int mt = 0; mt < 4; ++mt) {
      f32x4 s0 = __builtin_amdgcn_mfma_f32_16x16x32_bf16(kf0, qf[mt], zero, 0, 0, 0);
      f32x4 s1 = __builtin_amdgcn_mfma_f32_16x16x32_bf16(kf1, qf[mt], zero, 0, 0, 0);
      float e0 = __expf(s0[0]), e1 = __expf(s0[1]), e2 = __expf(s0[2]), e3 = __expf(s0[3]);
      float e4 = __expf(s1[0]), e5 = __expf(s1[1]), e6 = __expf(s1[2]), e7 = __expf(s1[3]);
      lp[mt] += ((e0 + e1) + (e2 + e3)) + ((e4 + e5) + (e6 + e7));
      union { bf16_t h[8]; bf16x8 v8; } pk_;
      pk_.h[0] = (bf16_t)e0; pk_.h[1] = (bf16_t)e1;
      pk_.h[2] = (bf16_t)e2; pk_.h[3] = (bf16_t)e3;
      pk_.h[4] = (bf16_t)e4; pk_.h[5] = (bf16_t)e5;
      pk_.h[6] = (bf16_t)e6; pk_.h[7] = (bf16_t)e7;
      pf[mt] = pk_.v8;
    }

    // ---- PV: O[m][c] += P.V^T ----
    __builtin_amdgcn_s_setprio(1);
#pragma unroll
    for (int ct = 0; ct < 4; ++ct)
#pragma unroll
      for (int mt = 0; mt < 4; ++mt)
        acc[mt][ct] = __builtin_amdgcn_mfma_f32_16x16x32_bf16(
            pf[mt], vf[ct], acc[mt][ct], 0, 0, 0);
    __builtin_amdgcn_s_setprio(0);

    kf0 = kf0n; kf1 = kf1n;
#pragma unroll
    for (int ct = 0; ct < 4; ++ct) vf[ct] = vfn[ct];
  }

  // ---- denom reduce (wave-local) + epilogue ----
  const float g = gamma[0];
#pragma unroll
  for (int mt = 0; mt < 4; ++mt) {
    float s = lp[mt];
    s += __shfl_xor(s, 16);
    s += __shfl_xor(s, 32);  // now lanes (lo, *) all hold total for m = mt*16+lo
    f32x4 linv;
#pragma unroll
    for (int r = 0; r < 4; ++r) linv[r] = 1.0f / __shfl(s, q4 * 4 + r);
#pragma unroll
    for (int ct = 0; ct < 4; ++ct) {
      const size_t row = (size_t)(b * CC + cb + ct * 16 + lo) * NN
                       + m0 + mt * 16 + q4 * 4;
      float4 xv = *(const float4*)(x + row);
      float4 ov;
      ov.x = g * acc[mt][ct][0] * linv[0] + xv.x;
      ov.y = g * acc[mt][ct][1] * linv[1] + xv.y;
      ov.z = g * acc[mt][ct][2] * linv[2] + xv.z;
      ov.w = g * acc[mt][ct][3] * linv[3] + xv.w;
      *(float4*)(out + row) = ov;
    }
  }
}

// ---------------------------------------------------------------------------
extern "C" void kernel_launch(void* const* d_in, const int* in_sizes, int n_in,
                              void* d_out, int out_size, void* d_ws, size_t ws_size,
                              hipStream_t stream) {
  const float* x     = (const float*)d_in[0];
  const float* Wq    = (const float*)d_in[1];
  const float* bq    = (const float*)d_in[2];
  const float* Wk    = (const float*)d_in[3];
  const float* bk    = (const float*)d_in[4];
  const float* Wv    = (const float*)d_in[5];
  const float* bv    = (const float*)d_in[6];
  const float* gamma = (const float*)d_in[7];
  float* out = (float*)d_out;

  // Workspace (bf16): q 2MB, k 2MB, v 16MB, Wb 160KB, xt 16MB (~36.2MB)
  bf16_t* ws = (bf16_t*)d_ws;
  bf16_t* q  = ws;
  bf16_t* k  = q + (size_t)BB * NN * II;
  bf16_t* v  = k + (size_t)BB * NN * II;
  bf16_t* Wb = v + (size_t)BB * CC * NN;
  bf16_t* xt = Wb + (size_t)320 * 256;

  wconv<<<dim3(320), 256, 0, stream>>>(Wq, Wk, Wv, Wb);

  dim3 gx(NN / 64, CC / 64, BB);
  xcvt<<<gx, 256, 0, stream>>>(x, xt);

  dim3 gp(NN / 128, 4, BB);
  qkv_proj<<<gp, 256, 0, stream>>>(xt, Wb, bq, bk, bv, q, k, v);

  attn_zs<<<dim3(512), 256, 0, stream>>>(q, k, v, x, gamma, out);
}